// Round 12
// baseline (84.704 us; speedup 1.0000x reference)
//
#include <hip/hip_runtime.h>

#define N 64
#define MARGIN 0.1f
#define WAVES_PER_BLOCK 4
#define NBLOCKS 2048

// closed form (verified R2..R11, absmax 0.0): row_loss = sum_e u_e*(q_e - p_e)
//   p_e = #{k: lab_k < lab_e},  u_e = sc_e - MARGIN*p_e,  q_e = #{k: u_k < u_e}
//
// R12 = R11 (vcc-free sign-bit counting, confirmed -4.2 us) + pass-2 pipe
// split. R11's LDS pipe (1 ds_write + 16 ds_read_b128/row, shared by 4
// SIMDs) binds at ~11 us/CU vs VALU ~5.6. Move half of pass-2 supply to
// v_readlane (VALU): LDS ~5.6 us, VALU ~6 us -- balanced. (R9 tested this
// split but under vcc serialization, which masked it.)
__global__ __launch_bounds__(256) void mmrl_partial(const float* __restrict__ scores,
                                                    const float* __restrict__ labels,
                                                    float* __restrict__ partial,
                                                    int rows) {
    __shared__ float ubuf[WAVES_PER_BLOCK][N];
    __shared__ float wsum[WAVES_PER_BLOCK];

    const int lane = threadIdx.x & 63;
    const int w    = threadIdx.x >> 6;
    const int gwave = blockIdx.x * WAVES_PER_BLOCK + w;
    const int nwaves = NBLOCKS * WAVES_PER_BLOCK;

    float acc = 0.0f;

    for (int row = gwave; row < rows; row += nwaves) {
        const int base = __builtin_amdgcn_readfirstlane(row) * N;
        const float labv = labels[base + lane];   // coalesced per-lane copy
        const float scv  = scores[base + lane];

        // ---- pass 1: label rank p (SMEM float4 broadcasts; sign-bit counts) ----
        const float4* L4 = (const float4*)(labels + base);
        int p0 = 0, p1 = 0, p2 = 0, p3 = 0;       // accumulate 0 / -1
        #pragma unroll
        for (int kk = 0; kk < N / 4; ++kk) {
            const float4 a = L4[kk];
            p0 += __float_as_int(a.x - labv) >> 31;
            p1 += __float_as_int(a.y - labv) >> 31;
            p2 += __float_as_int(a.z - labv) >> 31;
            p3 += __float_as_int(a.w - labv) >> 31;
        }
        const int pv = -((p0 + p1) + (p2 + p3));

        const float u = fmaf(-MARGIN, (float)pv, scv);
        const int ub = __float_as_int(u);

        // stage u for the LDS half of pass 2
        ubuf[w][lane] = u;

        // ---- pass 2b first: elems 32..63 via v_readlane (VALU supply),
        //      overlaps the LDS write/read latency ----
        int q0 = 0, q1 = 0, q2 = 0, q3 = 0;
        #pragma unroll
        for (int e = 32; e < 64; e += 4) {
            const float x0 = __int_as_float(__builtin_amdgcn_readlane(ub, e));
            const float x1 = __int_as_float(__builtin_amdgcn_readlane(ub, e + 1));
            const float x2 = __int_as_float(__builtin_amdgcn_readlane(ub, e + 2));
            const float x3 = __int_as_float(__builtin_amdgcn_readlane(ub, e + 3));
            q0 += __float_as_int(x0 - u) >> 31;
            q1 += __float_as_int(x1 - u) >> 31;
            q2 += __float_as_int(x2 - u) >> 31;
            q3 += __float_as_int(x3 - u) >> 31;
        }

        // ---- pass 2a: elems 0..31 via LDS uniform float4 broadcasts ----
        asm volatile("s_waitcnt lgkmcnt(0)" ::: "memory");  // intra-wave LDS in-order
        const float4* U4 = (const float4*)ubuf[w];
        #pragma unroll
        for (int kk = 0; kk < 8; ++kk) {
            const float4 a = U4[kk];
            q0 += __float_as_int(a.x - u) >> 31;
            q1 += __float_as_int(a.y - u) >> 31;
            q2 += __float_as_int(a.z - u) >> 31;
            q3 += __float_as_int(a.w - u) >> 31;
        }
        const int qv = -((q0 + q1) + (q2 + q3));

        acc = fmaf(u, (float)(qv - pv), acc);
    }

    // ---- wave reduction ----
    #pragma unroll
    for (int off = 32; off > 0; off >>= 1)
        acc += __shfl_down(acc, off, 64);

    if (lane == 0) wsum[w] = acc;
    __syncthreads();
    if (threadIdx.x == 0) {
        float s = 0.0f;
        #pragma unroll
        for (int i = 0; i < WAVES_PER_BLOCK; ++i) s += wsum[i];
        partial[blockIdx.x] = s;          // plain store, no atomic, no fence
    }
}

__global__ __launch_bounds__(256) void mmrl_reduce(const float* __restrict__ partial,
                                                   float* __restrict__ out,
                                                   int npartial, float inv_rows) {
    const int t = threadIdx.x;
    float s = 0.0f;
    for (int i = t; i < npartial; i += 256)
        s += partial[i];
    #pragma unroll
    for (int off = 32; off > 0; off >>= 1)
        s += __shfl_down(s, off, 64);
    __shared__ float wsum[4];
    if ((t & 63) == 0) wsum[t >> 6] = s;
    __syncthreads();
    if (t == 0)
        out[0] = (wsum[0] + wsum[1] + wsum[2] + wsum[3]) * inv_rows;
}

extern "C" void kernel_launch(void* const* d_in, const int* in_sizes, int n_in,
                              void* d_out, int out_size, void* d_ws, size_t ws_size,
                              hipStream_t stream) {
    const float* scores = (const float*)d_in[0];
    const float* labels = (const float*)d_in[1];
    float* out = (float*)d_out;
    float* partial = (float*)d_ws;        // 2048 floats = 8 KB << ws_size
    const int rows = in_sizes[0] / N;     // 32768

    mmrl_partial<<<NBLOCKS, 256, 0, stream>>>(scores, labels, partial, rows);
    mmrl_reduce<<<1, 256, 0, stream>>>(partial, out, NBLOCKS, 1.0f / (float)rows);
}

// Round 13
// 84.342 us; speedup vs baseline: 1.0043x; 1.0043x over previous
//
#include <hip/hip_runtime.h>

#define N 64
#define MARGIN 0.1f
#define WAVES_PER_BLOCK 4
#define NBLOCKS 2048

// closed form (verified R2..R12, absmax 0.0): row_loss = sum_e u_e*(q_e - p_e)
//   p_e = #{k: lab_k < lab_e},  u_e = sc_e - MARGIN*p_e,  q_e = #{k: u_k < u_e}
//
// R13 = R11 (best, 80.1us: sign-bit vcc-free counting, pass1 SMEM float4,
// pass2 LDS float4, two kernels/plain stores) + DUAL-ROW interleave.
// R10 profile showed VALUBusy 21%, occupancy 50%, HBM 1% -> latency-bound on
// the per-row dependent chain (load->pass1->u->ds_write->ds_read->pass2).
// Two independent row chains per wave let pass1(B) overlap pass2(A).
// (R5's interleave was masked by vcc serialization; R7's pipeline spilled --
// here: no prefetch, no launch_bounds cap, 2 rows only.)
__global__ __launch_bounds__(256) void mmrl_partial(const float* __restrict__ scores,
                                                    const float* __restrict__ labels,
                                                    float* __restrict__ partial,
                                                    int rows) {
    __shared__ float ubufA[WAVES_PER_BLOCK][N];
    __shared__ float ubufB[WAVES_PER_BLOCK][N];
    __shared__ float wsum[WAVES_PER_BLOCK];

    const int lane = threadIdx.x & 63;
    const int w    = threadIdx.x >> 6;
    const int gwave = blockIdx.x * WAVES_PER_BLOCK + w;
    const int nwaves = NBLOCKS * WAVES_PER_BLOCK;

    float acc = 0.0f;

    for (int row = gwave; row < rows; row += 2 * nwaves) {
        const int rA = row;
        const int rB = row + nwaves;
        const bool hasB = rB < rows;
        const int baseA = __builtin_amdgcn_readfirstlane(rA) * N;
        const int baseB = __builtin_amdgcn_readfirstlane(hasB ? rB : rA) * N;

        const float labA = labels[baseA + lane];
        const float scA  = scores[baseA + lane];
        const float labB = labels[baseB + lane];
        const float scB  = scores[baseB + lane];

        // ---- pass 1 (both rows, SMEM float4 broadcasts, sign-bit counts) ----
        const float4* LA = (const float4*)(labels + baseA);
        const float4* LB = (const float4*)(labels + baseB);
        int pA0 = 0, pA1 = 0, pA2 = 0, pA3 = 0;
        int pB0 = 0, pB1 = 0, pB2 = 0, pB3 = 0;
        #pragma unroll
        for (int kk = 0; kk < N / 4; ++kk) {
            const float4 a = LA[kk];
            const float4 b = LB[kk];
            pA0 += __float_as_int(a.x - labA) >> 31;
            pA1 += __float_as_int(a.y - labA) >> 31;
            pA2 += __float_as_int(a.z - labA) >> 31;
            pA3 += __float_as_int(a.w - labA) >> 31;
            pB0 += __float_as_int(b.x - labB) >> 31;
            pB1 += __float_as_int(b.y - labB) >> 31;
            pB2 += __float_as_int(b.z - labB) >> 31;
            pB3 += __float_as_int(b.w - labB) >> 31;
        }
        const int pA = -((pA0 + pA1) + (pA2 + pA3));
        const int pB = -((pB0 + pB1) + (pB2 + pB3));

        const float uA = fmaf(-MARGIN, (float)pA, scA);
        const float uB = fmaf(-MARGIN, (float)pB, scB);

        // ---- stage u for both rows, one waitcnt ----
        ubufA[w][lane] = uA;
        ubufB[w][lane] = uB;
        asm volatile("s_waitcnt lgkmcnt(0)" ::: "memory");  // intra-wave LDS in-order

        // ---- pass 2 (both rows, LDS uniform float4 broadcasts) ----
        const float4* UA = (const float4*)ubufA[w];
        const float4* UB = (const float4*)ubufB[w];
        int qA0 = 0, qA1 = 0, qA2 = 0, qA3 = 0;
        int qB0 = 0, qB1 = 0, qB2 = 0, qB3 = 0;
        #pragma unroll
        for (int kk = 0; kk < N / 4; ++kk) {
            const float4 a = UA[kk];
            const float4 b = UB[kk];
            qA0 += __float_as_int(a.x - uA) >> 31;
            qA1 += __float_as_int(a.y - uA) >> 31;
            qA2 += __float_as_int(a.z - uA) >> 31;
            qA3 += __float_as_int(a.w - uA) >> 31;
            qB0 += __float_as_int(b.x - uB) >> 31;
            qB1 += __float_as_int(b.y - uB) >> 31;
            qB2 += __float_as_int(b.z - uB) >> 31;
            qB3 += __float_as_int(b.w - uB) >> 31;
        }
        const int qA = -((qA0 + qA1) + (qA2 + qA3));
        const int qB = -((qB0 + qB1) + (qB2 + qB3));

        acc = fmaf(uA, (float)(qA - pA), acc);
        const float cB = uB * (float)(qB - pB);
        acc += hasB ? cB : 0.0f;
    }

    // ---- wave reduction ----
    #pragma unroll
    for (int off = 32; off > 0; off >>= 1)
        acc += __shfl_down(acc, off, 64);

    if (lane == 0) wsum[w] = acc;
    __syncthreads();
    if (threadIdx.x == 0) {
        float s = 0.0f;
        #pragma unroll
        for (int i = 0; i < WAVES_PER_BLOCK; ++i) s += wsum[i];
        partial[blockIdx.x] = s;          // plain store, no atomic, no fence
    }
}

__global__ __launch_bounds__(256) void mmrl_reduce(const float* __restrict__ partial,
                                                   float* __restrict__ out,
                                                   int npartial, float inv_rows) {
    const int t = threadIdx.x;
    float s = 0.0f;
    for (int i = t; i < npartial; i += 256)
        s += partial[i];
    #pragma unroll
    for (int off = 32; off > 0; off >>= 1)
        s += __shfl_down(s, off, 64);
    __shared__ float wsum[4];
    if ((t & 63) == 0) wsum[t >> 6] = s;
    __syncthreads();
    if (t == 0)
        out[0] = (wsum[0] + wsum[1] + wsum[2] + wsum[3]) * inv_rows;
}

extern "C" void kernel_launch(void* const* d_in, const int* in_sizes, int n_in,
                              void* d_out, int out_size, void* d_ws, size_t ws_size,
                              hipStream_t stream) {
    const float* scores = (const float*)d_in[0];
    const float* labels = (const float*)d_in[1];
    float* out = (float*)d_out;
    float* partial = (float*)d_ws;        // 2048 floats = 8 KB << ws_size
    const int rows = in_sizes[0] / N;     // 32768

    mmrl_partial<<<NBLOCKS, 256, 0, stream>>>(scores, labels, partial, rows);
    mmrl_reduce<<<1, 256, 0, stream>>>(partial, out, NBLOCKS, 1.0f / (float)rows);
}

// Round 14
// 84.034 us; speedup vs baseline: 1.0080x; 1.0037x over previous
//
#include <hip/hip_runtime.h>

#define N 64
#define MARGIN 0.1f
#define WAVES_PER_BLOCK 4
#define NBLOCKS 2048

// closed form (verified R2..R13, absmax 0.0): row_loss = sum_e u_e*(q_e - p_e)
//   p_e = #{k: lab_k < lab_e},  u_e = sc_e - MARGIN*p_e,  q_e = #{k: u_k < u_e}
//
// R14: pass-2 rank eliminated via  sum_e u_e*q_e = (N-1)/2 * sum_e u_e
//   + 1/4 * sum_{e,k} |u_e - u_k|   (max(a,b) = (a+b+|a-b|)/2 over pairs).
// Per-lane:  c_e = u_e*(31.5 - p_e) + 0.25 * sum_k |u_e - u_k|.
// Pass 2 is now 2 VALU ops/element (v_sub + v_add with abs modifier),
// pure-float independent chains, no rank ints, no convert tail.
// Pass 1 (sign-bit vcc-free counting, SMEM float4 broadcasts) and the
// two-kernel plain-store reduction are unchanged from R11 (best, 80.1 us).
__global__ __launch_bounds__(256) void mmrl_partial(const float* __restrict__ scores,
                                                    const float* __restrict__ labels,
                                                    float* __restrict__ partial,
                                                    int rows) {
    __shared__ float ubuf[WAVES_PER_BLOCK][N];
    __shared__ float wsum[WAVES_PER_BLOCK];

    const int lane = threadIdx.x & 63;
    const int w    = threadIdx.x >> 6;
    const int gwave = blockIdx.x * WAVES_PER_BLOCK + w;
    const int nwaves = NBLOCKS * WAVES_PER_BLOCK;

    float acc = 0.0f;

    for (int row = gwave; row < rows; row += nwaves) {
        const int base = __builtin_amdgcn_readfirstlane(row) * N;
        const float labv = labels[base + lane];   // coalesced per-lane copy
        const float scv  = scores[base + lane];

        // ---- pass 1: label rank p (SMEM float4 broadcasts; sign-bit counts) ----
        const float4* L4 = (const float4*)(labels + base);
        int p0 = 0, p1 = 0, p2 = 0, p3 = 0;       // accumulate 0 / -1
        #pragma unroll
        for (int kk = 0; kk < N / 4; ++kk) {
            const float4 a = L4[kk];
            p0 += __float_as_int(a.x - labv) >> 31;
            p1 += __float_as_int(a.y - labv) >> 31;
            p2 += __float_as_int(a.z - labv) >> 31;
            p3 += __float_as_int(a.w - labv) >> 31;
        }
        const int pv = -((p0 + p1) + (p2 + p3));

        const float u = fmaf(-MARGIN, (float)pv, scv);

        // ---- pass 2: sum_k |u - u_k| (LDS uniform float4 broadcasts) ----
        ubuf[w][lane] = u;
        asm volatile("s_waitcnt lgkmcnt(0)" ::: "memory");  // intra-wave LDS in-order
        const float4* U4 = (const float4*)ubuf[w];
        float A0 = 0.0f, A1 = 0.0f, A2 = 0.0f, A3 = 0.0f;
        #pragma unroll
        for (int kk = 0; kk < N / 4; ++kk) {
            const float4 a = U4[kk];
            A0 += fabsf(a.x - u);                  // v_add_f32 with |..| modifier
            A1 += fabsf(a.y - u);
            A2 += fabsf(a.z - u);
            A3 += fabsf(a.w - u);
        }
        const float rowabs = (A0 + A1) + (A2 + A3);

        // c = u*( (N-1)/2 - p ) + rowabs/4
        acc = fmaf(u, 31.5f - (float)pv, fmaf(0.25f, rowabs, acc));
    }

    // ---- wave reduction ----
    #pragma unroll
    for (int off = 32; off > 0; off >>= 1)
        acc += __shfl_down(acc, off, 64);

    if (lane == 0) wsum[w] = acc;
    __syncthreads();
    if (threadIdx.x == 0) {
        float s = 0.0f;
        #pragma unroll
        for (int i = 0; i < WAVES_PER_BLOCK; ++i) s += wsum[i];
        partial[blockIdx.x] = s;          // plain store, no atomic, no fence
    }
}

__global__ __launch_bounds__(256) void mmrl_reduce(const float* __restrict__ partial,
                                                   float* __restrict__ out,
                                                   int npartial, float inv_rows) {
    const int t = threadIdx.x;
    float s = 0.0f;
    for (int i = t; i < npartial; i += 256)
        s += partial[i];
    #pragma unroll
    for (int off = 32; off > 0; off >>= 1)
        s += __shfl_down(s, off, 64);
    __shared__ float wsum[4];
    if ((t & 63) == 0) wsum[t >> 6] = s;
    __syncthreads();
    if (t == 0)
        out[0] = (wsum[0] + wsum[1] + wsum[2] + wsum[3]) * inv_rows;
}

extern "C" void kernel_launch(void* const* d_in, const int* in_sizes, int n_in,
                              void* d_out, int out_size, void* d_ws, size_t ws_size,
                              hipStream_t stream) {
    const float* scores = (const float*)d_in[0];
    const float* labels = (const float*)d_in[1];
    float* out = (float*)d_out;
    float* partial = (float*)d_ws;        // 2048 floats = 8 KB << ws_size
    const int rows = in_sizes[0] / N;     // 32768

    mmrl_partial<<<NBLOCKS, 256, 0, stream>>>(scores, labels, partial, rows);
    mmrl_reduce<<<1, 256, 0, stream>>>(partial, out, NBLOCKS, 1.0f / (float)rows);
}